// Round 1
// baseline (757.666 us; speedup 1.0000x reference)
//
#include <hip/hip_runtime.h>

typedef _Float16 h8 __attribute__((ext_vector_type(8)));
typedef _Float16 h4 __attribute__((ext_vector_type(4)));
typedef float f4 __attribute__((ext_vector_type(4)));

#define MFMA16(a, b, c) __builtin_amdgcn_mfma_f32_16x16x32_f16((a), (b), (c), 0, 0, 0)

// B=4, S=4096, D_IN=D_OUT=512 (fixed by setup_inputs)

// ---------------- weight convert: Wt[z][n][k] = W_z[k][n] * (z==0 ? 0.5 : 1) ----------------
// 0.5 folds the reference's scores/2.0 into Q. B-operands need k-contiguous rows -> transpose.
__global__ void wconv_kernel(const float* __restrict__ Wq, const float* __restrict__ Wk,
                             const float* __restrict__ Wv, _Float16* __restrict__ Wt) {
  int idx = blockIdx.x * 256 + threadIdx.x;  // 3 * 512 * 64 threads, 8 elems each
  int z = idx >> 15;
  int rem = idx & 32767;
  int n = rem >> 6;
  int k0 = (rem & 63) << 3;
  const float* W = (z == 0) ? Wq : (z == 1) ? Wk : Wv;
  float sc = (z == 0) ? 0.5f : 1.0f;
  h8 v;
#pragma unroll
  for (int j = 0; j < 8; ++j) v[j] = (_Float16)(W[(k0 + j) * 512 + n] * sc);
  *(h8*)&Wt[(size_t)z * 262144 + n * 512 + k0] = v;
}

// ---------------- QKV projection: C[16384x512] = x @ W + b, x converted to fp16 in staging ----
// 128x128 tile, 4 waves, BK=64 single-buffered LDS (+8-half pad -> b128 floor, no conflicts).
// z=0 -> Qh (scaled 0.5), z=1 -> Kh, z=2 -> Vt (transposed [b][d][s] for PV B-operand).
__global__ __launch_bounds__(256, 2)
void proj_kernel(const float* __restrict__ x, const _Float16* __restrict__ Wt,
                 const float* __restrict__ bq, const float* __restrict__ bk,
                 const float* __restrict__ bv,
                 _Float16* __restrict__ Qh, _Float16* __restrict__ Kh, _Float16* __restrict__ Vt) {
  __shared__ _Float16 sA[128 * 72];
  __shared__ _Float16 sB[128 * 72];
  const int tid = threadIdx.x;
  const int wave = tid >> 6, lane = tid & 63;
  const int quad = lane >> 4, lr = lane & 15;
  const int mbase = blockIdx.x * 128;
  const int nbase = blockIdx.y * 128;
  const int z = blockIdx.z;
  const _Float16* W = Wt + (size_t)z * 262144;

  const int sr = tid >> 1;    // staging row 0..127
  const int sseg = tid & 1;   // 2 segs x 32 halfs

  const int rbase = (wave & 1) * 64;
  const int cbase = (wave >> 1) * 64;

  float4 ax[2][8];
  int4 bx[2][4];

  f4 acc[4][4];
#pragma unroll
  for (int i = 0; i < 4; ++i)
#pragma unroll
    for (int j = 0; j < 4; ++j) {
      f4 zz = {0.f, 0.f, 0.f, 0.f};
      acc[i][j] = zz;
    }

  {  // preload kt = 0
    const float4* asrc = (const float4*)&x[(size_t)(mbase + sr) * 512 + sseg * 32];
#pragma unroll
    for (int i = 0; i < 8; ++i) ax[0][i] = asrc[i];
    const int4* bsrc = (const int4*)&W[(size_t)(nbase + sr) * 512 + sseg * 32];
#pragma unroll
    for (int i = 0; i < 4; ++i) bx[0][i] = bsrc[i];
  }

#pragma unroll
  for (int kt = 0; kt < 8; ++kt) {
    const int p = kt & 1;
    // stage current chunk to LDS (fp32 -> fp16 convert for A)
#pragma unroll
    for (int i = 0; i < 4; ++i) {
      h8 v;
      float4 f0 = ax[p][2 * i], f1 = ax[p][2 * i + 1];
      v[0] = (_Float16)f0.x; v[1] = (_Float16)f0.y; v[2] = (_Float16)f0.z; v[3] = (_Float16)f0.w;
      v[4] = (_Float16)f1.x; v[5] = (_Float16)f1.y; v[6] = (_Float16)f1.z; v[7] = (_Float16)f1.w;
      *(h8*)&sA[sr * 72 + sseg * 32 + i * 8] = v;
    }
#pragma unroll
    for (int i = 0; i < 4; ++i) *(int4*)&sB[sr * 72 + sseg * 32 + i * 8] = bx[p][i];

    if (kt + 1 < 8) {  // prefetch next chunk into the other reg buffer
      const float4* asrc = (const float4*)&x[(size_t)(mbase + sr) * 512 + (kt + 1) * 64 + sseg * 32];
#pragma unroll
      for (int i = 0; i < 8; ++i) ax[p ^ 1][i] = asrc[i];
      const int4* bsrc = (const int4*)&W[(size_t)(nbase + sr) * 512 + (kt + 1) * 64 + sseg * 32];
#pragma unroll
      for (int i = 0; i < 4; ++i) bx[p ^ 1][i] = bsrc[i];
    }
    __syncthreads();
#pragma unroll
    for (int ks = 0; ks < 2; ++ks) {
      h8 a[4], b[4];
#pragma unroll
      for (int rt = 0; rt < 4; ++rt)
        a[rt] = *(const h8*)&sA[(rbase + rt * 16 + lr) * 72 + ks * 32 + quad * 8];
#pragma unroll
      for (int ct = 0; ct < 4; ++ct)
        b[ct] = *(const h8*)&sB[(cbase + ct * 16 + lr) * 72 + ks * 32 + quad * 8];
#pragma unroll
      for (int rt = 0; rt < 4; ++rt)
#pragma unroll
        for (int ct = 0; ct < 4; ++ct)
          acc[rt][ct] = MFMA16(a[rt], b[ct], acc[rt][ct]);
    }
    __syncthreads();
  }

  const float* bias = (z == 0) ? bq : (z == 1) ? bk : bv;
  const float bscale = (z == 0) ? 0.5f : 1.0f;
  _Float16* outQK = (z == 0) ? Qh : Kh;
#pragma unroll
  for (int ct = 0; ct < 4; ++ct) {
    const int col = nbase + cbase + ct * 16 + lr;
    const float bb = bias[col] * bscale;
#pragma unroll
    for (int rt = 0; rt < 4; ++rt) {
      const int row0 = mbase + rbase + rt * 16 + quad * 4;  // C-layout: row = quad*4 + reg
      if (z == 2) {
        const int bidx = row0 >> 12, s = row0 & 4095;
        h4 v;
#pragma unroll
        for (int r = 0; r < 4; ++r) v[r] = (_Float16)(acc[rt][ct][r] + bb);
        *(h4*)&Vt[(size_t)bidx * 2097152 + (size_t)col * 4096 + s] = v;
      } else {
#pragma unroll
        for (int r = 0; r < 4; ++r)
          outQK[(size_t)(row0 + r) * 512 + col] = (_Float16)(acc[rt][ct][r] + bb);
      }
    }
  }
}

// ---------------- fused flash attention ----------------
// 1 WG = 64 Q-rows x 512 d; 8 waves (512 thr); Q frags in regs (64 VGPR/lane).
// Per 64-key step: 4x K d-chunk stages (dbuf LDS + 2-deep global reg prefetch) -> S AGPRs
// -> sS (C->A layout via LDS) -> online softmax -> rescale O -> 4x V^T d-chunk stages -> PV.
__global__ __launch_bounds__(512, 2)
void attn_kernel(const _Float16* __restrict__ Qh, const _Float16* __restrict__ Kh,
                 const _Float16* __restrict__ Vt, float* __restrict__ out) {
  __shared__ _Float16 sKV[2][9216];  // K chunk [64][136] or V^T chunk [128][72]
  __shared__ float sS[64 * 68];
  __shared__ _Float16 sP[64 * 72];
  __shared__ float sM[64];
  __shared__ float sL[64];
  __shared__ float sAl[64];

  const int tid = threadIdx.x;
  const int wave = tid >> 6, lane = tid & 63;
  const int quad = lane >> 4, lr = lane & 15;
  const int b = blockIdx.y;
  const int qbase = blockIdx.x * 64;
  const int rowg = (wave & 3) * 16;    // this wave's S/O row group
  const int colg = (wave >> 2) * 32;   // this wave's S key-column half
  const int vcolg = (wave >> 2) * 64;  // this wave's O col slice within each 128-d chunk

  const int krow = tid >> 3, kseg = tid & 7;  // K staging: 64 rows x 8 segs x 32B
  const int vrow = tid >> 2, vseg = tid & 3;  // V staging: 128 rows x 4 segs x 32B

  const _Float16* Kb = Kh + (size_t)b * 4096 * 512;
  const _Float16* Vb = Vt + (size_t)b * 512 * 4096;

  int4 ra[2], rb[2];

  auto issue = [&](int p, int cc, int kb) {
    const int4* src;
    if (cc < 4) {
      src = (const int4*)&Kb[(size_t)(kb + krow) * 512 + cc * 128 + kseg * 16];
    } else {
      src = (const int4*)&Vb[(size_t)((cc - 4) * 128 + vrow) * 4096 + kb + vseg * 16];
    }
    ra[p] = src[0];
    rb[p] = src[1];
  };

  if (tid < 64) { sM[tid] = -1e30f; sL[tid] = 0.f; }

  // Q fragments: A-layout row = lane&15, k = quad*8 + j; qf[f] covers k = f*32 + quad*8
  h8 qf[16];
  {
    const int grow = qbase + rowg + lr;
    const _Float16* qp = Qh + (size_t)(b * 4096 + grow) * 512 + quad * 8;
#pragma unroll
    for (int f = 0; f < 16; ++f) qf[f] = *(const h8*)&qp[f * 32];
  }

  f4 o[4][4];
#pragma unroll
  for (int i = 0; i < 4; ++i)
#pragma unroll
    for (int j = 0; j < 4; ++j) { f4 zz = {0.f, 0.f, 0.f, 0.f}; o[i][j] = zz; }

  issue(0, 0, 0);
  issue(1, 1, 0);

  const int smr = tid >> 3, smc = (tid & 7) << 3;

  for (int step = 0; step < 64; ++step) {
    const int kb = step << 6;
    f4 sacc[2];
    { f4 zz = {0.f, 0.f, 0.f, 0.f}; sacc[0] = zz; sacc[1] = zz; }

    // ---- QK phase ----
#pragma unroll
    for (int c = 0; c < 4; ++c) {
      const int p = c & 1;
      __syncthreads();  // buf p free (reader of 2 chunks ago done)
      {
        int4* d = (int4*)&sKV[p][krow * 136 + kseg * 16];
        d[0] = ra[p]; d[1] = rb[p];
      }
      issue(p, c + 2, kb);  // 2-chunk-deep prefetch (c+2 in {2,3} = K, {4,5} = V0/V1)
      __syncthreads();
#pragma unroll
      for (int ks = 0; ks < 4; ++ks) {
        const h8 a = qf[c * 4 + ks];
#pragma unroll
        for (int t2 = 0; t2 < 2; ++t2) {
          const h8 bf = *(const h8*)&sKV[p][(colg + t2 * 16 + lr) * 136 + ks * 32 + quad * 8];
          sacc[t2] = MFMA16(a, bf, sacc[t2]);
        }
      }
    }

    // ---- S -> LDS (C-layout write) ----
#pragma unroll
    for (int t2 = 0; t2 < 2; ++t2)
#pragma unroll
      for (int r = 0; r < 4; ++r)
        sS[(rowg + quad * 4 + r) * 68 + colg + t2 * 16 + lr] = sacc[t2][r];

    __syncthreads();

    // ---- online softmax: 8 lanes per row ----
    {
      float4 v0 = *(const float4*)&sS[smr * 68 + smc];
      float4 v1 = *(const float4*)&sS[smr * 68 + smc + 4];
      float tm = fmaxf(fmaxf(fmaxf(v0.x, v0.y), fmaxf(v0.z, v0.w)),
                       fmaxf(fmaxf(v1.x, v1.y), fmaxf(v1.z, v1.w)));
      tm = fmaxf(tm, __shfl_xor(tm, 1));
      tm = fmaxf(tm, __shfl_xor(tm, 2));
      tm = fmaxf(tm, __shfl_xor(tm, 4));
      const float m_old = sM[smr];
      const float m_new = fmaxf(m_old, tm);
      float p0 = __expf(v0.x - m_new), p1 = __expf(v0.y - m_new),
            p2 = __expf(v0.z - m_new), p3 = __expf(v0.w - m_new),
            p4 = __expf(v1.x - m_new), p5 = __expf(v1.y - m_new),
            p6 = __expf(v1.z - m_new), p7 = __expf(v1.w - m_new);
      float sum = ((p0 + p1) + (p2 + p3)) + ((p4 + p5) + (p6 + p7));
      sum += __shfl_xor(sum, 1);
      sum += __shfl_xor(sum, 2);
      sum += __shfl_xor(sum, 4);
      const float alpha = __expf(m_old - m_new);
      h8 ph;
      ph[0] = (_Float16)p0; ph[1] = (_Float16)p1; ph[2] = (_Float16)p2; ph[3] = (_Float16)p3;
      ph[4] = (_Float16)p4; ph[5] = (_Float16)p5; ph[6] = (_Float16)p6; ph[7] = (_Float16)p7;
      *(h8*)&sP[smr * 72 + smc] = ph;
      if ((tid & 7) == 0) {
        sM[smr] = m_new;
        sL[smr] = sL[smr] * alpha + sum;
        sAl[smr] = alpha;
      }
    }
    __syncthreads();

    // ---- rescale O by alpha (row depends only on reg slot) ----
    {
      float al[4];
#pragma unroll
      for (int r = 0; r < 4; ++r) al[r] = sAl[rowg + quad * 4 + r];
#pragma unroll
      for (int c4 = 0; c4 < 4; ++c4)
#pragma unroll
        for (int ct = 0; ct < 4; ++ct)
#pragma unroll
          for (int r = 0; r < 4; ++r) o[c4][ct][r] *= al[r];
    }

    // ---- PV phase ----
#pragma unroll
    for (int c = 0; c < 4; ++c) {
      const int p = c & 1;
      if (c > 0) __syncthreads();
      {
        int4* d = (int4*)&sKV[p][vrow * 72 + vseg * 16];
        d[0] = ra[p]; d[1] = rb[p];
      }
      {
        int ncc = 6 + c, nkb = kb;  // prefetch V2/V3, then next step's K0/K1
        if (ncc >= 8) { ncc -= 8; nkb += 64; }
        if (nkb < 4096) issue(p, ncc, nkb);
      }
      __syncthreads();
#pragma unroll
      for (int ks2 = 0; ks2 < 2; ++ks2) {
        const h8 pf = *(const h8*)&sP[(rowg + lr) * 72 + ks2 * 32 + quad * 8];
#pragma unroll
        for (int ct = 0; ct < 4; ++ct) {
          const h8 vf = *(const h8*)&sKV[p][(vcolg + ct * 16 + lr) * 72 + ks2 * 32 + quad * 8];
          o[c][ct] = MFMA16(pf, vf, o[c][ct]);
        }
      }
    }
  }

  // ---- epilogue: O / l ----
  float li[4];
#pragma unroll
  for (int r = 0; r < 4; ++r) li[r] = 1.0f / sL[rowg + quad * 4 + r];
#pragma unroll
  for (int c4 = 0; c4 < 4; ++c4)
#pragma unroll
    for (int ct = 0; ct < 4; ++ct) {
      const int col = c4 * 128 + vcolg + ct * 16 + lr;
#pragma unroll
      for (int r = 0; r < 4; ++r) {
        const int row = qbase + rowg + quad * 4 + r;
        out[((size_t)b * 4096 + row) * 512 + col] = o[c4][ct][r] * li[r];
      }
    }
}

extern "C" void kernel_launch(void* const* d_in, const int* in_sizes, int n_in,
                              void* d_out, int out_size, void* d_ws, size_t ws_size,
                              hipStream_t stream) {
  (void)in_sizes; (void)n_in; (void)out_size; (void)ws_size;
  const float* x  = (const float*)d_in[0];
  const float* Wq = (const float*)d_in[1];
  const float* bq = (const float*)d_in[2];
  const float* Wk = (const float*)d_in[3];
  const float* bk = (const float*)d_in[4];
  const float* Wv = (const float*)d_in[5];
  const float* bv = (const float*)d_in[6];
  float* out = (float*)d_out;
  char* ws = (char*)d_ws;
  // ws layout: Qh @0 (16MB), Kh @16MB, Vt @32MB (transposed [b][d][s]), Wt @48MB (3x 512KB)
  _Float16* Qh = (_Float16*)(ws);
  _Float16* Kh = (_Float16*)(ws + ((size_t)1 << 24));
  _Float16* Vt = (_Float16*)(ws + ((size_t)2 << 24));
  _Float16* Wt = (_Float16*)(ws + ((size_t)3 << 24));

  wconv_kernel<<<dim3(384), dim3(256), 0, stream>>>(Wq, Wk, Wv, Wt);
  proj_kernel<<<dim3(128, 4, 3), dim3(256), 0, stream>>>(x, Wt, bq, bk, bv, Qh, Kh, Vt);
  attn_kernel<<<dim3(64, 4), dim3(512), 0, stream>>>(Qh, Kh, Vt, out);
}